// Round 3
// baseline (281.909 us; speedup 1.0000x reference)
//
#include <hip/hip_runtime.h>
#include <math.h>

#define NN 4096
#define DD 256
#define HH 4
#define SPLIT 8
#define BKG 64

typedef short short8 __attribute__((ext_vector_type(8)));
typedef float float4v __attribute__((ext_vector_type(4)));

__device__ __forceinline__ unsigned short f2bf(float f) {
  unsigned u = __float_as_uint(f);
  u += 0x7FFF + ((u >> 16) & 1);   // RNE
  return (unsigned short)(u >> 16);
}
__device__ __forceinline__ unsigned f2bf_pk(float a, float b) {
  unsigned ua = __float_as_uint(a); ua += 0x7FFF + ((ua >> 16) & 1);
  unsigned ub = __float_as_uint(b); ub += 0x7FFF + ((ub >> 16) & 1);
  return __builtin_amdgcn_perm(ub, ua, 0x07060302);
}
__device__ __forceinline__ void gld16(void* lds, const void* gp) {
  __builtin_amdgcn_global_load_lds(
      (const __attribute__((address_space(1))) unsigned int*)gp,
      (__attribute__((address_space(3))) unsigned int*)lds, 16, 0, 0);
}

// ---------------- zero hp (atomic fallback only) ----------------
__global__ void k_zero(float* __restrict__ hp) {
  int idx = blockIdx.x * 256 + threadIdx.x;
  ((float4*)hp)[idx] = make_float4(0.f, 0.f, 0.f, 0.f);
}

// ======= k_pre: blocks 0..255 transpose x->hbfT; blocks 256..319 scores =======
// Rp[h][i] = exp(s1), Ebf[h][j] = bf16(exp(s2)); unshifted softmax is safe:
// e <= s1+s2 < ~40, exp(40)=2e17 << fp32 max
__global__ __launch_bounds__(256) void k_pre(
    const float* __restrict__ x, const float* __restrict__ a,
    const float* __restrict__ cwp, const float* __restrict__ cbp,
    unsigned short* __restrict__ hbfT, float* __restrict__ Rpg,
    unsigned short* __restrict__ Ebf) {
  const int tid = threadIdx.x;
  const int bid = blockIdx.x;
  const float cw = cwp[0], cb = cbp[0];

  if (bid < 256) {
    __shared__ float t[64][65];
    const int j0 = (bid & 63) * 64, d0 = (bid >> 6) * 64;
    const int r = tid >> 4, c4 = tid & 15;
#pragma unroll
    for (int p = 0; p < 4; p++) {
      const int jj = p * 16 + r;
      const float4 v = *(const float4*)(x + (size_t)(j0 + jj) * DD + d0 + c4 * 4);
      t[jj][c4 * 4 + 0] = v.x * cw + cb;
      t[jj][c4 * 4 + 1] = v.y * cw + cb;
      t[jj][c4 * 4 + 2] = v.z * cw + cb;
      t[jj][c4 * 4 + 3] = v.w * cw + cb;
    }
    __syncthreads();
    const int jc = (tid & 15) * 4, db = tid >> 4;
#pragma unroll
    for (int p = 0; p < 4; p++) {
      const int dd = p * 16 + db;
      const unsigned l0 = f2bf(t[jc + 0][dd]);
      const unsigned l1 = f2bf(t[jc + 1][dd]);
      const unsigned l2 = f2bf(t[jc + 2][dd]);
      const unsigned l3 = f2bf(t[jc + 3][dd]);
      uint2 val;
      val.x = l0 | (l1 << 16);
      val.y = l2 | (l3 << 16);
      *(uint2*)(hbfT + (size_t)(d0 + dd) * NN + j0 + jc) = val;
    }
  } else {
    const int ln = tid >> 2, qd = (tid & 3) * 64;
    const int node = (bid - 256) * 64 + ln;
    float p1[HH] = {0.f, 0.f, 0.f, 0.f}, p2[HH] = {0.f, 0.f, 0.f, 0.f};
#pragma unroll
    for (int k = 0; k < 16; k++) {
      const int d = qd + k * 4;
      const float4 v = *(const float4*)(x + (size_t)node * DD + d);
      const float h0 = v.x * cw + cb, h1 = v.y * cw + cb;
      const float h2 = v.z * cw + cb, h3 = v.w * cw + cb;
#pragma unroll
      for (int h = 0; h < HH; h++) {
        const float4 a1 = *(const float4*)(a + h * 512 + d);
        const float4 a2 = *(const float4*)(a + h * 512 + 256 + d);
        p1[h] += h0 * a1.x + h1 * a1.y + h2 * a1.z + h3 * a1.w;
        p2[h] += h0 * a2.x + h1 * a2.y + h2 * a2.z + h3 * a2.w;
      }
    }
#pragma unroll
    for (int off = 1; off <= 2; off <<= 1) {
#pragma unroll
      for (int h = 0; h < HH; h++) {
        p1[h] += __shfl_xor(p1[h], off);
        p2[h] += __shfl_xor(p2[h], off);
      }
    }
    if ((tid & 3) == 0) {
#pragma unroll
      for (int h = 0; h < HH; h++) {
        Rpg[h * NN + node] = __expf(p1[h]);
        Ebf[h * NN + node] = f2bf(__expf(p2[h]));
      }
    }
  }
}

// ======= k_zw: 1 row/block, unshifted softmax, f32 register P (no repack) =======
// p = exp(elu(t)): t>0 (u>1) -> u ; t<=0 -> exp(u-1) = C*exp(u) (ternary required:
// exp(u-1) >= u for ALL u, so min/max folds are mathematically wrong)
// Also zeroes the split-K counters (block 0) -- stream-ordered before k_gemm.
__global__ __launch_bounds__(256) void k_zw(
    const int* __restrict__ adj, const float* __restrict__ Rpg,
    const unsigned short* __restrict__ Ebf, unsigned short* __restrict__ Wm,
    int* __restrict__ cnt) {
  __shared__ float red[4][HH];
  __shared__ float sZi[HH];

  const int i = blockIdx.x;
  const int tid = threadIdx.x;
  if (i == 0 && tid < 64) cnt[tid] = 0;
  const float C = 0.36787944117144233f;   // e^-1
  float Rp[HH], z[HH];
#pragma unroll
  for (int h = 0; h < HH; h++) {
    Rp[h] = Rpg[h * NN + i];
    z[h] = 0.f;
  }
  float P[4][HH][4];
  const int4* arow = (const int4*)(adj + (size_t)i * NN);
#pragma unroll
  for (int k = 0; k < 4; k++) {
    const int j4 = tid + k * 256;
    const int4 av = arow[j4];
    const bool m0 = av.x > 0, m1 = av.y > 0, m2 = av.z > 0, m3 = av.w > 0;
#pragma unroll
    for (int h = 0; h < HH; h++) {
      const uint2 e2 = *(const uint2*)(Ebf + (size_t)h * NN + j4 * 4);
      const float E0 = __uint_as_float(e2.x << 16);
      const float E1 = __uint_as_float(e2.x & 0xffff0000u);
      const float E2 = __uint_as_float(e2.y << 16);
      const float E3 = __uint_as_float(e2.y & 0xffff0000u);
      float u, p0, p1, p2, p3;
      u = Rp[h] * E0; p0 = u > 1.f ? u : C * __expf(u); p0 = m0 ? p0 : 0.f;
      u = Rp[h] * E1; p1 = u > 1.f ? u : C * __expf(u); p1 = m1 ? p1 : 0.f;
      u = Rp[h] * E2; p2 = u > 1.f ? u : C * __expf(u); p2 = m2 ? p2 : 0.f;
      u = Rp[h] * E3; p3 = u > 1.f ? u : C * __expf(u); p3 = m3 ? p3 : 0.f;
      z[h] += (p0 + p1) + (p2 + p3);
      P[k][h][0] = p0; P[k][h][1] = p1; P[k][h][2] = p2; P[k][h][3] = p3;
    }
  }
#pragma unroll
  for (int h = 0; h < HH; h++) {
#pragma unroll
    for (int off = 32; off; off >>= 1) z[h] += __shfl_xor(z[h], off);
  }
  const int lane = tid & 63, wv = tid >> 6;
  if (lane == 0) {
#pragma unroll
    for (int h = 0; h < HH; h++) red[wv][h] = z[h];
  }
  __syncthreads();
  if (tid < HH) {
    const float zt = red[0][tid] + red[1][tid] + red[2][tid] + red[3][tid];
    sZi[tid] = zt > 0.f ? 0.25f / zt : 0.f;
  }
  __syncthreads();
  float Zi[HH];
#pragma unroll
  for (int h = 0; h < HH; h++) Zi[h] = sZi[h];

  unsigned* wrow = (unsigned*)(Wm + (size_t)i * NN);
#pragma unroll
  for (int k = 0; k < 4; k++) {
    const int j4 = tid + k * 256;
    float w0 = 0.f, w1 = 0.f, w2 = 0.f, w3 = 0.f;
#pragma unroll
    for (int h = 0; h < HH; h++) {
      w0 += P[k][h][0] * Zi[h];
      w1 += P[k][h][1] * Zi[h];
      w2 += P[k][h][2] * Zi[h];
      w3 += P[k][h][3] * Zi[h];
    }
    wrow[j4 * 2] = f2bf_pk(w0, w1);
    wrow[j4 * 2 + 1] = f2bf_pk(w2, w3);
  }
}

// ======= k_gemm: MFMA GEMM, counted-vmcnt pipeline + fused split-K epilogue ======
// SPLIT=8 -> 512 blocks = 2/CU (80KB LDS x2 = 160KB budget). Per tile each thread
// issues 10 global_load_lds (2 A + 8 B); steady-state s_waitcnt vmcnt(10) = "prev
// tile landed" while next tile flies across both raw barriers.
// Epilogue: last block of each 64-row group (device-scope atomic counter +
// __threadfence release/acquire) sums the 8 partials and writes final out --
// removes the k_epi kernel boundary entirely.
__global__ __launch_bounds__(256) void k_gemm(
    const unsigned short* __restrict__ Wm, const unsigned short* __restrict__ hbfT,
    float* __restrict__ hpOut, int useSplit, int* __restrict__ cnt,
    const float* __restrict__ x, const float* __restrict__ cwp,
    const float* __restrict__ cbp, const float* __restrict__ bias,
    float* __restrict__ outp) {
  extern __shared__ __align__(16) unsigned short smem[];
  unsigned short* sA0 = smem;                // 64*64
  unsigned short* sA1 = smem + 4096;         // 64*64
  unsigned short* sB0 = smem + 8192;         // 256*64
  unsigned short* sB1 = smem + 8192 + 16384; // 256*64
  const int tid = threadIdx.x;
  const int wv = tid >> 6, lane = tid & 63;
  const int m16 = lane & 15, q = lane >> 4, m7 = m16 & 7;
  const int rb = blockIdx.x >> 3, sp = blockIdx.x & 7;
  const int i0 = rb * 64;
  const int jlo = sp * (NN / SPLIT);
  const int lr = lane >> 3;
  const int lk8 = (lane & 7) ^ lr;
  const int NT = (NN / SPLIT) / BKG;   // 8

  float4v acc[4][4];
#pragma unroll
  for (int a = 0; a < 4; a++)
#pragma unroll
    for (int b = 0; b < 4; b++) acc[a][b] = (float4v)0.f;

  // prologue: stage tile 0 into buffer 0 (10 loads/thread)
  {
    const int j0 = jlo;
#pragma unroll
    for (int t = 0; t < 2; t++) {
      const int r0 = wv * 16 + t * 8;
      gld16(sA0 + r0 * 64, Wm + (size_t)(i0 + r0 + lr) * NN + j0 + lk8 * 8);
    }
#pragma unroll
    for (int t = 0; t < 8; t++) {
      const int r0 = wv * 64 + t * 8;
      gld16(sB0 + r0 * 64, hbfT + (size_t)(r0 + lr) * NN + j0 + lk8 * 8);
    }
  }

  for (int kt = 0; kt < NT; kt++) {
    const unsigned short* sAb = (kt & 1) ? sA1 : sA0;
    const unsigned short* sBb = (kt & 1) ? sB1 : sB0;
    unsigned short* sAn = (kt & 1) ? sA0 : sA1;
    unsigned short* sBn = (kt & 1) ? sB0 : sB1;

    // issue next tile's loads; they stay in flight across both barriers below
    if (kt + 1 < NT) {
      const int j0 = jlo + (kt + 1) * BKG;
#pragma unroll
      for (int t = 0; t < 2; t++) {
        const int r0 = wv * 16 + t * 8;
        gld16(sAn + r0 * 64, Wm + (size_t)(i0 + r0 + lr) * NN + j0 + lk8 * 8);
      }
#pragma unroll
      for (int t = 0; t < 8; t++) {
        const int r0 = wv * 64 + t * 8;
        gld16(sBn + r0 * 64, hbfT + (size_t)(r0 + lr) * NN + j0 + lk8 * 8);
      }
      asm volatile("s_waitcnt vmcnt(10)" ::: "memory");  // tile kt landed
    } else {
      asm volatile("s_waitcnt vmcnt(0)" ::: "memory");   // final tile landed
    }
    __builtin_amdgcn_s_barrier();        // raw barrier: prefetch NOT drained
    __builtin_amdgcn_sched_barrier(0);   // pin ds_reads behind barrier

    // compute current tile
#pragma unroll
    for (int ks = 0; ks < 2; ks++) {
      const int kp = ((ks * 4 + q) ^ m7) * 8;
      short8 aF[4], bF[4];
#pragma unroll
      for (int it = 0; it < 4; it++)
        aF[it] = *(const short8*)(sAb + (it * 16 + m16) * 64 + kp);
#pragma unroll
      for (int dt = 0; dt < 4; dt++)
        bF[dt] = *(const short8*)(sBb + (wv * 64 + dt * 16 + m16) * 64 + kp);
#pragma unroll
      for (int it = 0; it < 4; it++)
#pragma unroll
        for (int dt = 0; dt < 4; dt++)
          acc[it][dt] = __builtin_amdgcn_mfma_f32_16x16x32_bf16(aF[it], bF[dt], acc[it][dt], 0, 0, 0);
    }
    __builtin_amdgcn_sched_barrier(0);   // keep compute before the close barrier
    __builtin_amdgcn_s_barrier();        // all waves done reading buf[c]
  }

  if (useSplit) {
    float* base = hpOut + (size_t)sp * NN * DD;
#pragma unroll
    for (int it = 0; it < 4; it++)
#pragma unroll
      for (int dt = 0; dt < 4; dt++) {
        const int d = wv * 64 + dt * 16 + m16;
#pragma unroll
        for (int rg = 0; rg < 4; rg++)
          base[(size_t)(i0 + it * 16 + q * 4 + rg) * DD + d] = acc[it][dt][rg];
      }

    // ---- fused split-K epilogue: last block of this 64-row group finishes ----
    __threadfence();                     // release: partial visible device-wide
    __shared__ int sLast;
    if (tid == 0) sLast = (atomicAdd(&cnt[rb], 1) == SPLIT - 1);
    __syncthreads();
    if (!sLast) return;
    __threadfence();                     // acquire: see other blocks' partials

    const float cw = cwp[0], cb = cbp[0];
    const int row0 = i0 + wv * 16;       // wave wv owns rows [row0, row0+16)
    const int d4 = lane * 4;
#pragma unroll 2
    for (int r = 0; r < 16; r++) {
      const int i = row0 + r;
      float4 pv = make_float4(0.f, 0.f, 0.f, 0.f);
#pragma unroll
      for (int s = 0; s < SPLIT; s++) {
        const float4 t = *(const float4*)(hpOut + (size_t)s * NN * DD + (size_t)i * DD + d4);
        pv.x += t.x; pv.y += t.y; pv.z += t.z; pv.w += t.w;
      }
      const float4 xv = *(const float4*)(x + (size_t)i * DD + d4);
      float4 v;
      v.x = 0.5f * pv.x + 0.5f * (xv.x * cw + cb);
      v.y = 0.5f * pv.y + 0.5f * (xv.y * cw + cb);
      v.z = 0.5f * pv.z + 0.5f * (xv.z * cw + cb);
      v.w = 0.5f * pv.w + 0.5f * (xv.w * cw + cb);
      v.x = v.x > 0.f ? v.x : expm1f(v.x);
      v.y = v.y > 0.f ? v.y : expm1f(v.y);
      v.z = v.z > 0.f ? v.z : expm1f(v.z);
      v.w = v.w > 0.f ? v.w : expm1f(v.w);
      float ss = v.x * v.x + v.y * v.y + v.z * v.z + v.w * v.w;
#pragma unroll
      for (int off = 32; off; off >>= 1) ss += __shfl_xor(ss, off);
      const float inv = 1.f / fmaxf(sqrtf(ss), 1e-12f);
      const float4 bv = *(const float4*)(bias + d4);
      float4 o;
      o.x = v.x * inv + bv.x;
      o.y = v.y * inv + bv.y;
      o.z = v.z * inv + bv.z;
      o.w = v.w * inv + bv.w;
      *(float4*)(outp + (size_t)i * DD + d4) = o;
    }
  } else {
#pragma unroll
    for (int it = 0; it < 4; it++)
#pragma unroll
      for (int dt = 0; dt < 4; dt++) {
        const int d = wv * 64 + dt * 16 + m16;
#pragma unroll
        for (int rg = 0; rg < 4; rg++)
          atomicAdd(&hpOut[(size_t)(i0 + it * 16 + q * 4 + rg) * DD + d], acc[it][dt][rg]);
      }
  }
}

// ---------------- k_epi (fallback path only) ----------------
__global__ __launch_bounds__(256) void k_epi(
    const float* __restrict__ hp, int nsplit, const float* __restrict__ x,
    const float* __restrict__ cwp, const float* __restrict__ cbp,
    const float* __restrict__ bias, float* __restrict__ out) {
  const int lane = threadIdx.x & 63, wv = threadIdx.x >> 6;
  const int i = blockIdx.x * 4 + wv;
  const float cw = cwp[0], cb = cbp[0];
  const int d4 = lane * 4;
  float4 pv = make_float4(0.f, 0.f, 0.f, 0.f);
  for (int s = 0; s < nsplit; s++) {
    const float4 t = *(const float4*)(hp + (size_t)s * NN * DD + (size_t)i * DD + d4);
    pv.x += t.x; pv.y += t.y; pv.z += t.z; pv.w += t.w;
  }
  const float4 xv = *(const float4*)(x + (size_t)i * DD + d4);
  float4 v;
  v.x = 0.5f * pv.x + 0.5f * (xv.x * cw + cb);
  v.y = 0.5f * pv.y + 0.5f * (xv.y * cw + cb);
  v.z = 0.5f * pv.z + 0.5f * (xv.z * cw + cb);
  v.w = 0.5f * pv.w + 0.5f * (xv.w * cw + cb);
  v.x = v.x > 0.f ? v.x : expm1f(v.x);
  v.y = v.y > 0.f ? v.y : expm1f(v.y);
  v.z = v.z > 0.f ? v.z : expm1f(v.z);
  v.w = v.w > 0.f ? v.w : expm1f(v.w);
  float ss = v.x * v.x + v.y * v.y + v.z * v.z + v.w * v.w;
#pragma unroll
  for (int off = 32; off; off >>= 1) ss += __shfl_xor(ss, off);
  const float inv = 1.f / fmaxf(sqrtf(ss), 1e-12f);
  const float4 bv = *(const float4*)(bias + d4);
  float4 o;
  o.x = v.x * inv + bv.x;
  o.y = v.y * inv + bv.y;
  o.z = v.z * inv + bv.z;
  o.w = v.w * inv + bv.w;
  *(float4*)(out + (size_t)i * DD + d4) = o;
}

extern "C" void kernel_launch(void* const* d_in, const int* in_sizes, int n_in,
                              void* d_out, int out_size, void* d_ws, size_t ws_size,
                              hipStream_t stream) {
  const float* x = (const float*)d_in[0];
  const int* adj = (const int*)d_in[1];
  const float* cw = (const float*)d_in[2];
  const float* cb = (const float*)d_in[3];
  const float* a = (const float*)d_in[4];
  const float* bias = (const float*)d_in[5];
  float* out = (float*)d_out;
  float* ws = (float*)d_ws;

  // layout (float units): Rpg | Ebf | hbfT | Wm | hp | cnt
  float* Rpg = ws;                                        // 16384 floats
  unsigned short* Ebf = (unsigned short*)(ws + 16384);    // 16384 shorts
  unsigned short* hbfT = (unsigned short*)(ws + 24576);   // 1M shorts
  unsigned short* Wm = (unsigned short*)(ws + 24576 + 524288);  // 16M shorts
  float* hp = ws + 24576 + 524288 + 8388608;              // SPLIT * N * D floats
  int* cnt = (int*)(ws + 24576 + 524288 + 8388608 + (size_t)SPLIT * NN * DD);  // 64 ints

  const size_t needSplit =
      (size_t)(24576 + 524288 + 8388608 + (size_t)SPLIT * NN * DD + 64) * 4;
  const int useSplit = (ws_size >= needSplit) ? 1 : 0;
  const int nsplit = useSplit ? SPLIT : 1;

  // 80KB dynamic LDS for k_gemm (exceeds default 64KB cap)
  static int smemDone = 0;
  if (!smemDone) {
    (void)hipFuncSetAttribute((const void*)k_gemm,
                              hipFuncAttributeMaxDynamicSharedMemorySize, 81920);
    smemDone = 1;
  }

  if (!useSplit) hipLaunchKernelGGL(k_zero, dim3(NN * DD / 1024), dim3(256), 0, stream, hp);
  hipLaunchKernelGGL(k_pre, dim3(320), dim3(256), 0, stream, x, a, cw, cb, hbfT, Rpg, Ebf);
  hipLaunchKernelGGL(k_zw, dim3(NN), dim3(256), 0, stream, adj, Rpg, Ebf, Wm, cnt);
  hipLaunchKernelGGL(k_gemm, dim3(64 * SPLIT), dim3(256), 81920, stream,
                     Wm, hbfT, hp, useSplit, cnt, x, cw, cb, bias, out);
  if (!useSplit)
    hipLaunchKernelGGL(k_epi, dim3(1024), dim3(256), 0, stream, hp, nsplit, x, cw, cb, bias, out);
}

// Round 4
// 159.913 us; speedup vs baseline: 1.7629x; 1.7629x over previous
//
#include <hip/hip_runtime.h>
#include <math.h>

#define NN 4096
#define DD 256
#define HH 4
#define SPLIT 8
#define BKG 64

typedef short short8 __attribute__((ext_vector_type(8)));
typedef float float4v __attribute__((ext_vector_type(4)));

__device__ __forceinline__ unsigned short f2bf(float f) {
  unsigned u = __float_as_uint(f);
  u += 0x7FFF + ((u >> 16) & 1);   // RNE
  return (unsigned short)(u >> 16);
}
__device__ __forceinline__ unsigned f2bf_pk(float a, float b) {
  unsigned ua = __float_as_uint(a); ua += 0x7FFF + ((ua >> 16) & 1);
  unsigned ub = __float_as_uint(b); ub += 0x7FFF + ((ub >> 16) & 1);
  return __builtin_amdgcn_perm(ub, ua, 0x07060302);
}
// fp16 pack/unpack: partial sums are O(1) -- e5m10 range is ample and mantissa
// error (~5e-4 rel) is below the bf16 quantization floor already in Wm/hbfT.
__device__ __forceinline__ unsigned short f2h(float f) {
  _Float16 h = (_Float16)f;                       // v_cvt_f16_f32 (RNE)
  return __builtin_bit_cast(unsigned short, h);
}
__device__ __forceinline__ float h2f(unsigned short u) {
  _Float16 h = __builtin_bit_cast(_Float16, u);   // v_cvt_f32_f16
  return (float)h;
}
__device__ __forceinline__ void gld16(void* lds, const void* gp) {
  __builtin_amdgcn_global_load_lds(
      (const __attribute__((address_space(1))) unsigned int*)gp,
      (__attribute__((address_space(3))) unsigned int*)lds, 16, 0, 0);
}

// ---------------- zero hp (atomic fallback only) ----------------
__global__ void k_zero(float* __restrict__ hp) {
  int idx = blockIdx.x * 256 + threadIdx.x;
  ((float4*)hp)[idx] = make_float4(0.f, 0.f, 0.f, 0.f);
}

// ======= k_pre: blocks 0..255 transpose x->hbfT; blocks 256..319 scores =======
// Rp[h][i] = exp(s1), Ebf[h][j] = bf16(exp(s2)); unshifted softmax is safe:
// e <= s1+s2 < ~40, exp(40)=2e17 << fp32 max
__global__ __launch_bounds__(256) void k_pre(
    const float* __restrict__ x, const float* __restrict__ a,
    const float* __restrict__ cwp, const float* __restrict__ cbp,
    unsigned short* __restrict__ hbfT, float* __restrict__ Rpg,
    unsigned short* __restrict__ Ebf) {
  const int tid = threadIdx.x;
  const int bid = blockIdx.x;
  const float cw = cwp[0], cb = cbp[0];

  if (bid < 256) {
    __shared__ float t[64][65];
    const int j0 = (bid & 63) * 64, d0 = (bid >> 6) * 64;
    const int r = tid >> 4, c4 = tid & 15;
#pragma unroll
    for (int p = 0; p < 4; p++) {
      const int jj = p * 16 + r;
      const float4 v = *(const float4*)(x + (size_t)(j0 + jj) * DD + d0 + c4 * 4);
      t[jj][c4 * 4 + 0] = v.x * cw + cb;
      t[jj][c4 * 4 + 1] = v.y * cw + cb;
      t[jj][c4 * 4 + 2] = v.z * cw + cb;
      t[jj][c4 * 4 + 3] = v.w * cw + cb;
    }
    __syncthreads();
    const int jc = (tid & 15) * 4, db = tid >> 4;
#pragma unroll
    for (int p = 0; p < 4; p++) {
      const int dd = p * 16 + db;
      const unsigned l0 = f2bf(t[jc + 0][dd]);
      const unsigned l1 = f2bf(t[jc + 1][dd]);
      const unsigned l2 = f2bf(t[jc + 2][dd]);
      const unsigned l3 = f2bf(t[jc + 3][dd]);
      uint2 val;
      val.x = l0 | (l1 << 16);
      val.y = l2 | (l3 << 16);
      *(uint2*)(hbfT + (size_t)(d0 + dd) * NN + j0 + jc) = val;
    }
  } else {
    const int ln = tid >> 2, qd = (tid & 3) * 64;
    const int node = (bid - 256) * 64 + ln;
    float p1[HH] = {0.f, 0.f, 0.f, 0.f}, p2[HH] = {0.f, 0.f, 0.f, 0.f};
#pragma unroll
    for (int k = 0; k < 16; k++) {
      const int d = qd + k * 4;
      const float4 v = *(const float4*)(x + (size_t)node * DD + d);
      const float h0 = v.x * cw + cb, h1 = v.y * cw + cb;
      const float h2 = v.z * cw + cb, h3 = v.w * cw + cb;
#pragma unroll
      for (int h = 0; h < HH; h++) {
        const float4 a1 = *(const float4*)(a + h * 512 + d);
        const float4 a2 = *(const float4*)(a + h * 512 + 256 + d);
        p1[h] += h0 * a1.x + h1 * a1.y + h2 * a1.z + h3 * a1.w;
        p2[h] += h0 * a2.x + h1 * a2.y + h2 * a2.z + h3 * a2.w;
      }
    }
#pragma unroll
    for (int off = 1; off <= 2; off <<= 1) {
#pragma unroll
      for (int h = 0; h < HH; h++) {
        p1[h] += __shfl_xor(p1[h], off);
        p2[h] += __shfl_xor(p2[h], off);
      }
    }
    if ((tid & 3) == 0) {
#pragma unroll
      for (int h = 0; h < HH; h++) {
        Rpg[h * NN + node] = __expf(p1[h]);
        Ebf[h * NN + node] = f2bf(__expf(p2[h]));
      }
    }
  }
}

// ======= k_zw: 1 row/block, unshifted softmax, f32 register P (no repack) =======
// p = exp(elu(t)): t>0 (u>1) -> u ; t<=0 -> exp(u-1) = C*exp(u) (ternary required:
// exp(u-1) >= u for ALL u, so min/max folds are mathematically wrong)
__global__ __launch_bounds__(256) void k_zw(
    const int* __restrict__ adj, const float* __restrict__ Rpg,
    const unsigned short* __restrict__ Ebf, unsigned short* __restrict__ Wm) {
  __shared__ float red[4][HH];
  __shared__ float sZi[HH];

  const int i = blockIdx.x;
  const int tid = threadIdx.x;
  const float C = 0.36787944117144233f;   // e^-1
  float Rp[HH], z[HH];
#pragma unroll
  for (int h = 0; h < HH; h++) {
    Rp[h] = Rpg[h * NN + i];
    z[h] = 0.f;
  }
  float P[4][HH][4];
  const int4* arow = (const int4*)(adj + (size_t)i * NN);
#pragma unroll
  for (int k = 0; k < 4; k++) {
    const int j4 = tid + k * 256;
    const int4 av = arow[j4];
    const bool m0 = av.x > 0, m1 = av.y > 0, m2 = av.z > 0, m3 = av.w > 0;
#pragma unroll
    for (int h = 0; h < HH; h++) {
      const uint2 e2 = *(const uint2*)(Ebf + (size_t)h * NN + j4 * 4);
      const float E0 = __uint_as_float(e2.x << 16);
      const float E1 = __uint_as_float(e2.x & 0xffff0000u);
      const float E2 = __uint_as_float(e2.y << 16);
      const float E3 = __uint_as_float(e2.y & 0xffff0000u);
      float u, p0, p1, p2, p3;
      u = Rp[h] * E0; p0 = u > 1.f ? u : C * __expf(u); p0 = m0 ? p0 : 0.f;
      u = Rp[h] * E1; p1 = u > 1.f ? u : C * __expf(u); p1 = m1 ? p1 : 0.f;
      u = Rp[h] * E2; p2 = u > 1.f ? u : C * __expf(u); p2 = m2 ? p2 : 0.f;
      u = Rp[h] * E3; p3 = u > 1.f ? u : C * __expf(u); p3 = m3 ? p3 : 0.f;
      z[h] += (p0 + p1) + (p2 + p3);
      P[k][h][0] = p0; P[k][h][1] = p1; P[k][h][2] = p2; P[k][h][3] = p3;
    }
  }
#pragma unroll
  for (int h = 0; h < HH; h++) {
#pragma unroll
    for (int off = 32; off; off >>= 1) z[h] += __shfl_xor(z[h], off);
  }
  const int lane = tid & 63, wv = tid >> 6;
  if (lane == 0) {
#pragma unroll
    for (int h = 0; h < HH; h++) red[wv][h] = z[h];
  }
  __syncthreads();
  if (tid < HH) {
    const float zt = red[0][tid] + red[1][tid] + red[2][tid] + red[3][tid];
    sZi[tid] = zt > 0.f ? 0.25f / zt : 0.f;
  }
  __syncthreads();
  float Zi[HH];
#pragma unroll
  for (int h = 0; h < HH; h++) Zi[h] = sZi[h];

  unsigned* wrow = (unsigned*)(Wm + (size_t)i * NN);
#pragma unroll
  for (int k = 0; k < 4; k++) {
    const int j4 = tid + k * 256;
    float w0 = 0.f, w1 = 0.f, w2 = 0.f, w3 = 0.f;
#pragma unroll
    for (int h = 0; h < HH; h++) {
      w0 += P[k][h][0] * Zi[h];
      w1 += P[k][h][1] * Zi[h];
      w2 += P[k][h][2] * Zi[h];
      w3 += P[k][h][3] * Zi[h];
    }
    wrow[j4 * 2] = f2bf_pk(w0, w1);
    wrow[j4 * 2 + 1] = f2bf_pk(w2, w3);
  }
}

// ======= k_gemm: MFMA GEMM, counted-vmcnt pipeline, FP16 hp partials =======
// SPLIT=8 -> 512 blocks = 2/CU (80KB LDS x2 = 160KB). Per tile each thread issues
// 10 global_load_lds (2 A + 8 B); s_waitcnt vmcnt(10) = "prev tile landed" while
// next tile flies across both RAW barriers (no implicit vmcnt(0) drain).
// NO device fences anywhere (R3 lesson: fence -> L2 writeback storm on 8-XCD).
__global__ __launch_bounds__(256) void k_gemm(
    const unsigned short* __restrict__ Wm, const unsigned short* __restrict__ hbfT,
    float* __restrict__ hpF, unsigned short* __restrict__ hpH, int useSplit) {
  extern __shared__ __align__(16) unsigned short smem[];
  unsigned short* sA0 = smem;                // 64*64
  unsigned short* sA1 = smem + 4096;         // 64*64
  unsigned short* sB0 = smem + 8192;         // 256*64
  unsigned short* sB1 = smem + 8192 + 16384; // 256*64
  const int tid = threadIdx.x;
  const int wv = tid >> 6, lane = tid & 63;
  const int m16 = lane & 15, q = lane >> 4, m7 = m16 & 7;
  const int rb = blockIdx.x >> 3, sp = blockIdx.x & 7;
  const int i0 = rb * 64;
  const int jlo = sp * (NN / SPLIT);
  const int lr = lane >> 3;
  const int lk8 = (lane & 7) ^ lr;
  const int NT = (NN / SPLIT) / BKG;   // 8

  float4v acc[4][4];
#pragma unroll
  for (int a = 0; a < 4; a++)
#pragma unroll
    for (int b = 0; b < 4; b++) acc[a][b] = (float4v)0.f;

  // prologue: stage tile 0 into buffer 0 (10 loads/thread)
  {
    const int j0 = jlo;
#pragma unroll
    for (int t = 0; t < 2; t++) {
      const int r0 = wv * 16 + t * 8;
      gld16(sA0 + r0 * 64, Wm + (size_t)(i0 + r0 + lr) * NN + j0 + lk8 * 8);
    }
#pragma unroll
    for (int t = 0; t < 8; t++) {
      const int r0 = wv * 64 + t * 8;
      gld16(sB0 + r0 * 64, hbfT + (size_t)(r0 + lr) * NN + j0 + lk8 * 8);
    }
  }

  for (int kt = 0; kt < NT; kt++) {
    const unsigned short* sAb = (kt & 1) ? sA1 : sA0;
    const unsigned short* sBb = (kt & 1) ? sB1 : sB0;
    unsigned short* sAn = (kt & 1) ? sA0 : sA1;
    unsigned short* sBn = (kt & 1) ? sB0 : sB1;

    // issue next tile's loads; they stay in flight across both barriers below
    if (kt + 1 < NT) {
      const int j0 = jlo + (kt + 1) * BKG;
#pragma unroll
      for (int t = 0; t < 2; t++) {
        const int r0 = wv * 16 + t * 8;
        gld16(sAn + r0 * 64, Wm + (size_t)(i0 + r0 + lr) * NN + j0 + lk8 * 8);
      }
#pragma unroll
      for (int t = 0; t < 8; t++) {
        const int r0 = wv * 64 + t * 8;
        gld16(sBn + r0 * 64, hbfT + (size_t)(r0 + lr) * NN + j0 + lk8 * 8);
      }
      asm volatile("s_waitcnt vmcnt(10)" ::: "memory");  // tile kt landed
    } else {
      asm volatile("s_waitcnt vmcnt(0)" ::: "memory");   // final tile landed
    }
    __builtin_amdgcn_s_barrier();        // raw barrier: prefetch NOT drained
    __builtin_amdgcn_sched_barrier(0);   // pin ds_reads behind barrier

    // compute current tile
#pragma unroll
    for (int ks = 0; ks < 2; ks++) {
      const int kp = ((ks * 4 + q) ^ m7) * 8;
      short8 aF[4], bF[4];
#pragma unroll
      for (int it = 0; it < 4; it++)
        aF[it] = *(const short8*)(sAb + (it * 16 + m16) * 64 + kp);
#pragma unroll
      for (int dt = 0; dt < 4; dt++)
        bF[dt] = *(const short8*)(sBb + (wv * 64 + dt * 16 + m16) * 64 + kp);
#pragma unroll
      for (int it = 0; it < 4; it++)
#pragma unroll
        for (int dt = 0; dt < 4; dt++)
          acc[it][dt] = __builtin_amdgcn_mfma_f32_16x16x32_bf16(aF[it], bF[dt], acc[it][dt], 0, 0, 0);
    }
    __builtin_amdgcn_sched_barrier(0);   // keep compute before the close barrier
    __builtin_amdgcn_s_barrier();        // all waves done reading buf[c]
  }

  if (useSplit) {
    unsigned short* base = hpH + (size_t)sp * NN * DD;
#pragma unroll
    for (int it = 0; it < 4; it++)
#pragma unroll
      for (int dt = 0; dt < 4; dt++) {
        const int d = wv * 64 + dt * 16 + m16;
#pragma unroll
        for (int rg = 0; rg < 4; rg++)
          base[(size_t)(i0 + it * 16 + q * 4 + rg) * DD + d] = f2h(acc[it][dt][rg]);
      }
  } else {
#pragma unroll
    for (int it = 0; it < 4; it++)
#pragma unroll
      for (int dt = 0; dt < 4; dt++) {
        const int d = wv * 64 + dt * 16 + m16;
#pragma unroll
        for (int rg = 0; rg < 4; rg++)
          atomicAdd(&hpF[(size_t)(i0 + it * 16 + q * 4 + rg) * DD + d], acc[it][dt][rg]);
      }
  }
}

// ---------------- k_epi: fp16 partial sum (split path) or f32 (fallback) -------
__global__ __launch_bounds__(256) void k_epi(
    const float* __restrict__ hpF, const unsigned short* __restrict__ hpH,
    int useSplit, const float* __restrict__ x,
    const float* __restrict__ cwp, const float* __restrict__ cbp,
    const float* __restrict__ bias, float* __restrict__ out) {
  const int lane = threadIdx.x & 63, wv = threadIdx.x >> 6;
  const int i = blockIdx.x * 4 + wv;
  const float cw = cwp[0], cb = cbp[0];
  const int d4 = lane * 4;
  float4 pv = make_float4(0.f, 0.f, 0.f, 0.f);
  if (useSplit) {
#pragma unroll
    for (int s = 0; s < SPLIT; s++) {
      const ushort4 t = *(const ushort4*)(hpH + (size_t)s * NN * DD + (size_t)i * DD + d4);
      pv.x += h2f(t.x); pv.y += h2f(t.y); pv.z += h2f(t.z); pv.w += h2f(t.w);
    }
  } else {
    const float4 t = *(const float4*)(hpF + (size_t)i * DD + d4);
    pv.x = t.x; pv.y = t.y; pv.z = t.z; pv.w = t.w;
  }
  const float4 xv = *(const float4*)(x + (size_t)i * DD + d4);
  float4 v;
  v.x = 0.5f * pv.x + 0.5f * (xv.x * cw + cb);
  v.y = 0.5f * pv.y + 0.5f * (xv.y * cw + cb);
  v.z = 0.5f * pv.z + 0.5f * (xv.z * cw + cb);
  v.w = 0.5f * pv.w + 0.5f * (xv.w * cw + cb);
  v.x = v.x > 0.f ? v.x : expm1f(v.x);
  v.y = v.y > 0.f ? v.y : expm1f(v.y);
  v.z = v.z > 0.f ? v.z : expm1f(v.z);
  v.w = v.w > 0.f ? v.w : expm1f(v.w);
  float ss = v.x * v.x + v.y * v.y + v.z * v.z + v.w * v.w;
#pragma unroll
  for (int off = 32; off; off >>= 1) ss += __shfl_xor(ss, off);
  const float inv = 1.f / fmaxf(sqrtf(ss), 1e-12f);
  const float4 bv = *(const float4*)(bias + d4);
  float4 o;
  o.x = v.x * inv + bv.x;
  o.y = v.y * inv + bv.y;
  o.z = v.z * inv + bv.z;
  o.w = v.w * inv + bv.w;
  *(float4*)(out + (size_t)i * DD + d4) = o;
}

extern "C" void kernel_launch(void* const* d_in, const int* in_sizes, int n_in,
                              void* d_out, int out_size, void* d_ws, size_t ws_size,
                              hipStream_t stream) {
  const float* x = (const float*)d_in[0];
  const int* adj = (const int*)d_in[1];
  const float* cw = (const float*)d_in[2];
  const float* cb = (const float*)d_in[3];
  const float* a = (const float*)d_in[4];
  const float* bias = (const float*)d_in[5];
  float* out = (float*)d_out;
  float* ws = (float*)d_ws;

  // layout (float units): Rpg | Ebf | hbfT | Wm | hp
  float* Rpg = ws;                                        // 16384 floats
  unsigned short* Ebf = (unsigned short*)(ws + 16384);    // 16384 shorts
  unsigned short* hbfT = (unsigned short*)(ws + 24576);   // 1M shorts
  unsigned short* Wm = (unsigned short*)(ws + 24576 + 524288);  // 16M shorts
  float* hpF = ws + 24576 + 524288 + 8388608;             // fallback: NN*DD floats
  unsigned short* hpH = (unsigned short*)hpF;             // split: SPLIT*NN*DD halfs

  const size_t needSplit =
      (size_t)(24576 + 524288 + 8388608) * 4 + (size_t)SPLIT * NN * DD * 2;
  const int useSplit = (ws_size >= needSplit) ? 1 : 0;

  // 80KB dynamic LDS for k_gemm (exceeds default 64KB cap)
  static int smemDone = 0;
  if (!smemDone) {
    (void)hipFuncSetAttribute((const void*)k_gemm,
                              hipFuncAttributeMaxDynamicSharedMemorySize, 81920);
    smemDone = 1;
  }

  if (!useSplit) hipLaunchKernelGGL(k_zero, dim3(NN * DD / 1024), dim3(256), 0, stream, hpF);
  hipLaunchKernelGGL(k_pre, dim3(320), dim3(256), 0, stream, x, a, cw, cb, hbfT, Rpg, Ebf);
  hipLaunchKernelGGL(k_zw, dim3(NN), dim3(256), 0, stream, adj, Rpg, Ebf, Wm);
  hipLaunchKernelGGL(k_gemm, dim3(64 * SPLIT), dim3(256), 81920, stream,
                     Wm, hbfT, hpF, hpH, useSplit);
  hipLaunchKernelGGL(k_epi, dim3(1024), dim3(256), 0, stream,
                     hpF, hpH, useSplit, x, cw, cb, bias, out);
}

// Round 5
// 159.377 us; speedup vs baseline: 1.7688x; 1.0034x over previous
//
#include <hip/hip_runtime.h>
#include <math.h>

#define NN 4096
#define DD 256
#define HH 4
#define SPLIT 8
#define BKG 64

typedef short short8 __attribute__((ext_vector_type(8)));
typedef float float4v __attribute__((ext_vector_type(4)));

__device__ __forceinline__ unsigned short f2bf(float f) {
  unsigned u = __float_as_uint(f);
  u += 0x7FFF + ((u >> 16) & 1);   // RNE
  return (unsigned short)(u >> 16);
}
__device__ __forceinline__ unsigned f2bf_pk(float a, float b) {
  unsigned ua = __float_as_uint(a); ua += 0x7FFF + ((ua >> 16) & 1);
  unsigned ub = __float_as_uint(b); ub += 0x7FFF + ((ub >> 16) & 1);
  return __builtin_amdgcn_perm(ub, ua, 0x07060302);
}
// fp16 pack/unpack: partial sums are O(1) -- e5m10 range is ample and mantissa
// error (~5e-4 rel) is below the bf16 quantization floor already in Wm/hbfT.
__device__ __forceinline__ unsigned short f2h(float f) {
  _Float16 h = (_Float16)f;                       // v_cvt_f16_f32 (RNE)
  return __builtin_bit_cast(unsigned short, h);
}
__device__ __forceinline__ float h2f(unsigned short u) {
  _Float16 h = __builtin_bit_cast(_Float16, u);   // v_cvt_f32_f16
  return (float)h;
}
__device__ __forceinline__ void gld16(void* lds, const void* gp) {
  __builtin_amdgcn_global_load_lds(
      (const __attribute__((address_space(1))) unsigned int*)gp,
      (__attribute__((address_space(3))) unsigned int*)lds, 16, 0, 0);
}

// ---------------- zero hp (atomic fallback only) ----------------
__global__ void k_zero(float* __restrict__ hp) {
  int idx = blockIdx.x * 256 + threadIdx.x;
  ((float4*)hp)[idx] = make_float4(0.f, 0.f, 0.f, 0.f);
}

// ======= k_pre: scores only (64 blocks). Transpose moved into k_zw. =======
// Rp[h][i] = exp(s1), Ebf[h][j] = bf16(exp(s2)); unshifted softmax is safe:
// e <= s1+s2 < ~40, exp(40)=2e17 << fp32 max
__global__ __launch_bounds__(256) void k_pre(
    const float* __restrict__ x, const float* __restrict__ a,
    const float* __restrict__ cwp, const float* __restrict__ cbp,
    float* __restrict__ Rpg, unsigned short* __restrict__ Ebf) {
  const int tid = threadIdx.x;
  const float cw = cwp[0], cb = cbp[0];
  const int ln = tid >> 2, qd = (tid & 3) * 64;
  const int node = blockIdx.x * 64 + ln;
  float p1[HH] = {0.f, 0.f, 0.f, 0.f}, p2[HH] = {0.f, 0.f, 0.f, 0.f};
#pragma unroll
  for (int k = 0; k < 16; k++) {
    const int d = qd + k * 4;
    const float4 v = *(const float4*)(x + (size_t)node * DD + d);
    const float h0 = v.x * cw + cb, h1 = v.y * cw + cb;
    const float h2 = v.z * cw + cb, h3 = v.w * cw + cb;
#pragma unroll
    for (int h = 0; h < HH; h++) {
      const float4 a1 = *(const float4*)(a + h * 512 + d);
      const float4 a2 = *(const float4*)(a + h * 512 + 256 + d);
      p1[h] += h0 * a1.x + h1 * a1.y + h2 * a1.z + h3 * a1.w;
      p2[h] += h0 * a2.x + h1 * a2.y + h2 * a2.z + h3 * a2.w;
    }
  }
#pragma unroll
  for (int off = 1; off <= 2; off <<= 1) {
#pragma unroll
    for (int h = 0; h < HH; h++) {
      p1[h] += __shfl_xor(p1[h], off);
      p2[h] += __shfl_xor(p2[h], off);
    }
  }
  if ((tid & 3) == 0) {
#pragma unroll
    for (int h = 0; h < HH; h++) {
      Rpg[h * NN + node] = __expf(p1[h]);
      Ebf[h * NN + node] = f2bf(__expf(p2[h]));
    }
  }
}

// ======= k_zw: blocks 0..255 transpose x->hbfT (hidden under row work);
//         blocks 256..4351 = one softmax row each. =======
// Transpose output (hbfT) is consumed only by k_gemm (next launch) -- safe to
// co-schedule here; no k_zw block reads it. LDS is a union: transpose tile
// 64x65 f32 vs row-path 20-float reduction scratch.
// p = exp(elu(t)): t>0 (u>1) -> u ; t<=0 -> exp(u-1) = C*exp(u) (ternary required:
// exp(u-1) >= u for ALL u, so min/max folds are mathematically wrong)
__global__ __launch_bounds__(256) void k_zw(
    const int* __restrict__ adj, const float* __restrict__ Rpg,
    const unsigned short* __restrict__ Ebf, unsigned short* __restrict__ Wm,
    const float* __restrict__ x, const float* __restrict__ cwp,
    const float* __restrict__ cbp, unsigned short* __restrict__ hbfT) {
  __shared__ __align__(16) float shm[64 * 65];   // union: transpose tile / red scratch
  const int bid = blockIdx.x;
  const int tid = threadIdx.x;

  if (bid < 256) {
    // ---- transpose path: x (j,d) -> hbfT (d,j) bf16, with conv affine ----
    const float cw = cwp[0], cb = cbp[0];
    float (*t)[65] = (float(*)[65])shm;
    const int j0 = (bid & 63) * 64, d0 = (bid >> 6) * 64;
    const int r = tid >> 4, c4 = tid & 15;
#pragma unroll
    for (int p = 0; p < 4; p++) {
      const int jj = p * 16 + r;
      const float4 v = *(const float4*)(x + (size_t)(j0 + jj) * DD + d0 + c4 * 4);
      t[jj][c4 * 4 + 0] = v.x * cw + cb;
      t[jj][c4 * 4 + 1] = v.y * cw + cb;
      t[jj][c4 * 4 + 2] = v.z * cw + cb;
      t[jj][c4 * 4 + 3] = v.w * cw + cb;
    }
    __syncthreads();
    const int jc = (tid & 15) * 4, db = tid >> 4;
#pragma unroll
    for (int p = 0; p < 4; p++) {
      const int dd = p * 16 + db;
      const unsigned l0 = f2bf(t[jc + 0][dd]);
      const unsigned l1 = f2bf(t[jc + 1][dd]);
      const unsigned l2 = f2bf(t[jc + 2][dd]);
      const unsigned l3 = f2bf(t[jc + 3][dd]);
      uint2 val;
      val.x = l0 | (l1 << 16);
      val.y = l2 | (l3 << 16);
      *(uint2*)(hbfT + (size_t)(d0 + dd) * NN + j0 + jc) = val;
    }
    return;
  }

  // ---- row path ----
  float* red = shm;        // [4][HH] = 16 floats
  float* sZi = shm + 16;   // [HH]
  const int i = bid - 256;
  const float C = 0.36787944117144233f;   // e^-1
  float Rp[HH], z[HH];
#pragma unroll
  for (int h = 0; h < HH; h++) {
    Rp[h] = Rpg[h * NN + i];
    z[h] = 0.f;
  }
  float P[4][HH][4];
  const int4* arow = (const int4*)(adj + (size_t)i * NN);
#pragma unroll
  for (int k = 0; k < 4; k++) {
    const int j4 = tid + k * 256;
    const int4 av = arow[j4];
    const bool m0 = av.x > 0, m1 = av.y > 0, m2 = av.z > 0, m3 = av.w > 0;
#pragma unroll
    for (int h = 0; h < HH; h++) {
      const uint2 e2 = *(const uint2*)(Ebf + (size_t)h * NN + j4 * 4);
      const float E0 = __uint_as_float(e2.x << 16);
      const float E1 = __uint_as_float(e2.x & 0xffff0000u);
      const float E2 = __uint_as_float(e2.y << 16);
      const float E3 = __uint_as_float(e2.y & 0xffff0000u);
      float u, p0, p1, p2, p3;
      u = Rp[h] * E0; p0 = u > 1.f ? u : C * __expf(u); p0 = m0 ? p0 : 0.f;
      u = Rp[h] * E1; p1 = u > 1.f ? u : C * __expf(u); p1 = m1 ? p1 : 0.f;
      u = Rp[h] * E2; p2 = u > 1.f ? u : C * __expf(u); p2 = m2 ? p2 : 0.f;
      u = Rp[h] * E3; p3 = u > 1.f ? u : C * __expf(u); p3 = m3 ? p3 : 0.f;
      z[h] += (p0 + p1) + (p2 + p3);
      P[k][h][0] = p0; P[k][h][1] = p1; P[k][h][2] = p2; P[k][h][3] = p3;
    }
  }
#pragma unroll
  for (int h = 0; h < HH; h++) {
#pragma unroll
    for (int off = 32; off; off >>= 1) z[h] += __shfl_xor(z[h], off);
  }
  const int lane = tid & 63, wv = tid >> 6;
  if (lane == 0) {
#pragma unroll
    for (int h = 0; h < HH; h++) red[wv * HH + h] = z[h];
  }
  __syncthreads();
  if (tid < HH) {
    const float zt = red[0 * HH + tid] + red[1 * HH + tid] +
                     red[2 * HH + tid] + red[3 * HH + tid];
    sZi[tid] = zt > 0.f ? 0.25f / zt : 0.f;
  }
  __syncthreads();
  float Zi[HH];
#pragma unroll
  for (int h = 0; h < HH; h++) Zi[h] = sZi[h];

  unsigned* wrow = (unsigned*)(Wm + (size_t)i * NN);
#pragma unroll
  for (int k = 0; k < 4; k++) {
    const int j4 = tid + k * 256;
    float w0 = 0.f, w1 = 0.f, w2 = 0.f, w3 = 0.f;
#pragma unroll
    for (int h = 0; h < HH; h++) {
      w0 += P[k][h][0] * Zi[h];
      w1 += P[k][h][1] * Zi[h];
      w2 += P[k][h][2] * Zi[h];
      w3 += P[k][h][3] * Zi[h];
    }
    wrow[j4 * 2] = f2bf_pk(w0, w1);
    wrow[j4 * 2 + 1] = f2bf_pk(w2, w3);
  }
}

// ======= k_gemm: MFMA GEMM, counted-vmcnt pipeline, FP16 hp partials =======
// SPLIT=8 -> 512 blocks = 2/CU (80KB LDS x2 = 160KB). Per tile each thread issues
// 10 global_load_lds (2 A + 8 B); s_waitcnt vmcnt(10) = "prev tile landed" while
// next tile flies across both RAW barriers (no implicit vmcnt(0) drain).
// NO device fences anywhere (R3 lesson: fence -> L2 writeback storm on 8-XCD).
__global__ __launch_bounds__(256) void k_gemm(
    const unsigned short* __restrict__ Wm, const unsigned short* __restrict__ hbfT,
    float* __restrict__ hpF, unsigned short* __restrict__ hpH, int useSplit) {
  extern __shared__ __align__(16) unsigned short smem[];
  unsigned short* sA0 = smem;                // 64*64
  unsigned short* sA1 = smem + 4096;         // 64*64
  unsigned short* sB0 = smem + 8192;         // 256*64
  unsigned short* sB1 = smem + 8192 + 16384; // 256*64
  const int tid = threadIdx.x;
  const int wv = tid >> 6, lane = tid & 63;
  const int m16 = lane & 15, q = lane >> 4, m7 = m16 & 7;
  const int rb = blockIdx.x >> 3, sp = blockIdx.x & 7;
  const int i0 = rb * 64;
  const int jlo = sp * (NN / SPLIT);
  const int lr = lane >> 3;
  const int lk8 = (lane & 7) ^ lr;
  const int NT = (NN / SPLIT) / BKG;   // 8

  float4v acc[4][4];
#pragma unroll
  for (int a = 0; a < 4; a++)
#pragma unroll
    for (int b = 0; b < 4; b++) acc[a][b] = (float4v)0.f;

  // prologue: stage tile 0 into buffer 0 (10 loads/thread)
  {
    const int j0 = jlo;
#pragma unroll
    for (int t = 0; t < 2; t++) {
      const int r0 = wv * 16 + t * 8;
      gld16(sA0 + r0 * 64, Wm + (size_t)(i0 + r0 + lr) * NN + j0 + lk8 * 8);
    }
#pragma unroll
    for (int t = 0; t < 8; t++) {
      const int r0 = wv * 64 + t * 8;
      gld16(sB0 + r0 * 64, hbfT + (size_t)(r0 + lr) * NN + j0 + lk8 * 8);
    }
  }

  for (int kt = 0; kt < NT; kt++) {
    const unsigned short* sAb = (kt & 1) ? sA1 : sA0;
    const unsigned short* sBb = (kt & 1) ? sB1 : sB0;
    unsigned short* sAn = (kt & 1) ? sA0 : sA1;
    unsigned short* sBn = (kt & 1) ? sB0 : sB1;

    // issue next tile's loads; they stay in flight across both barriers below
    if (kt + 1 < NT) {
      const int j0 = jlo + (kt + 1) * BKG;
#pragma unroll
      for (int t = 0; t < 2; t++) {
        const int r0 = wv * 16 + t * 8;
        gld16(sAn + r0 * 64, Wm + (size_t)(i0 + r0 + lr) * NN + j0 + lk8 * 8);
      }
#pragma unroll
      for (int t = 0; t < 8; t++) {
        const int r0 = wv * 64 + t * 8;
        gld16(sBn + r0 * 64, hbfT + (size_t)(r0 + lr) * NN + j0 + lk8 * 8);
      }
      asm volatile("s_waitcnt vmcnt(10)" ::: "memory");  // tile kt landed
    } else {
      asm volatile("s_waitcnt vmcnt(0)" ::: "memory");   // final tile landed
    }
    __builtin_amdgcn_s_barrier();        // raw barrier: prefetch NOT drained
    __builtin_amdgcn_sched_barrier(0);   // pin ds_reads behind barrier

    // compute current tile
#pragma unroll
    for (int ks = 0; ks < 2; ks++) {
      const int kp = ((ks * 4 + q) ^ m7) * 8;
      short8 aF[4], bF[4];
#pragma unroll
      for (int it = 0; it < 4; it++)
        aF[it] = *(const short8*)(sAb + (it * 16 + m16) * 64 + kp);
#pragma unroll
      for (int dt = 0; dt < 4; dt++)
        bF[dt] = *(const short8*)(sBb + (wv * 64 + dt * 16 + m16) * 64 + kp);
#pragma unroll
      for (int it = 0; it < 4; it++)
#pragma unroll
        for (int dt = 0; dt < 4; dt++)
          acc[it][dt] = __builtin_amdgcn_mfma_f32_16x16x32_bf16(aF[it], bF[dt], acc[it][dt], 0, 0, 0);
    }
    __builtin_amdgcn_sched_barrier(0);   // keep compute before the close barrier
    __builtin_amdgcn_s_barrier();        // all waves done reading buf[c]
  }

  if (useSplit) {
    unsigned short* base = hpH + (size_t)sp * NN * DD;
#pragma unroll
    for (int it = 0; it < 4; it++)
#pragma unroll
      for (int dt = 0; dt < 4; dt++) {
        const int d = wv * 64 + dt * 16 + m16;
#pragma unroll
        for (int rg = 0; rg < 4; rg++)
          base[(size_t)(i0 + it * 16 + q * 4 + rg) * DD + d] = f2h(acc[it][dt][rg]);
      }
  } else {
#pragma unroll
    for (int it = 0; it < 4; it++)
#pragma unroll
      for (int dt = 0; dt < 4; dt++) {
        const int d = wv * 64 + dt * 16 + m16;
#pragma unroll
        for (int rg = 0; rg < 4; rg++)
          atomicAdd(&hpF[(size_t)(i0 + it * 16 + q * 4 + rg) * DD + d], acc[it][dt][rg]);
      }
  }
}

// ---------------- k_epi: fp16 partial sum (split path) or f32 (fallback) -------
__global__ __launch_bounds__(256) void k_epi(
    const float* __restrict__ hpF, const unsigned short* __restrict__ hpH,
    int useSplit, const float* __restrict__ x,
    const float* __restrict__ cwp, const float* __restrict__ cbp,
    const float* __restrict__ bias, float* __restrict__ out) {
  const int lane = threadIdx.x & 63, wv = threadIdx.x >> 6;
  const int i = blockIdx.x * 4 + wv;
  const float cw = cwp[0], cb = cbp[0];
  const int d4 = lane * 4;
  float4 pv = make_float4(0.f, 0.f, 0.f, 0.f);
  if (useSplit) {
#pragma unroll
    for (int s = 0; s < SPLIT; s++) {
      const ushort4 t = *(const ushort4*)(hpH + (size_t)s * NN * DD + (size_t)i * DD + d4);
      pv.x += h2f(t.x); pv.y += h2f(t.y); pv.z += h2f(t.z); pv.w += h2f(t.w);
    }
  } else {
    const float4 t = *(const float4*)(hpF + (size_t)i * DD + d4);
    pv.x = t.x; pv.y = t.y; pv.z = t.z; pv.w = t.w;
  }
  const float4 xv = *(const float4*)(x + (size_t)i * DD + d4);
  float4 v;
  v.x = 0.5f * pv.x + 0.5f * (xv.x * cw + cb);
  v.y = 0.5f * pv.y + 0.5f * (xv.y * cw + cb);
  v.z = 0.5f * pv.z + 0.5f * (xv.z * cw + cb);
  v.w = 0.5f * pv.w + 0.5f * (xv.w * cw + cb);
  v.x = v.x > 0.f ? v.x : expm1f(v.x);
  v.y = v.y > 0.f ? v.y : expm1f(v.y);
  v.z = v.z > 0.f ? v.z : expm1f(v.z);
  v.w = v.w > 0.f ? v.w : expm1f(v.w);
  float ss = v.x * v.x + v.y * v.y + v.z * v.z + v.w * v.w;
#pragma unroll
  for (int off = 32; off; off >>= 1) ss += __shfl_xor(ss, off);
  const float inv = 1.f / fmaxf(sqrtf(ss), 1e-12f);
  const float4 bv = *(const float4*)(bias + d4);
  float4 o;
  o.x = v.x * inv + bv.x;
  o.y = v.y * inv + bv.y;
  o.z = v.z * inv + bv.z;
  o.w = v.w * inv + bv.w;
  *(float4*)(out + (size_t)i * DD + d4) = o;
}

extern "C" void kernel_launch(void* const* d_in, const int* in_sizes, int n_in,
                              void* d_out, int out_size, void* d_ws, size_t ws_size,
                              hipStream_t stream) {
  const float* x = (const float*)d_in[0];
  const int* adj = (const int*)d_in[1];
  const float* cw = (const float*)d_in[2];
  const float* cb = (const float*)d_in[3];
  const float* a = (const float*)d_in[4];
  const float* bias = (const float*)d_in[5];
  float* out = (float*)d_out;
  float* ws = (float*)d_ws;

  // layout (float units): Rpg | Ebf | hbfT | Wm | hp
  float* Rpg = ws;                                        // 16384 floats
  unsigned short* Ebf = (unsigned short*)(ws + 16384);    // 16384 shorts
  unsigned short* hbfT = (unsigned short*)(ws + 24576);   // 1M shorts
  unsigned short* Wm = (unsigned short*)(ws + 24576 + 524288);  // 16M shorts
  float* hpF = ws + 24576 + 524288 + 8388608;             // fallback: NN*DD floats
  unsigned short* hpH = (unsigned short*)hpF;             // split: SPLIT*NN*DD halfs

  const size_t needSplit =
      (size_t)(24576 + 524288 + 8388608) * 4 + (size_t)SPLIT * NN * DD * 2;
  const int useSplit = (ws_size >= needSplit) ? 1 : 0;

  // 80KB dynamic LDS for k_gemm (exceeds default 64KB cap)
  static int smemDone = 0;
  if (!smemDone) {
    (void)hipFuncSetAttribute((const void*)k_gemm,
                              hipFuncAttributeMaxDynamicSharedMemorySize, 81920);
    smemDone = 1;
  }

  if (!useSplit) hipLaunchKernelGGL(k_zero, dim3(NN * DD / 1024), dim3(256), 0, stream, hpF);
  hipLaunchKernelGGL(k_pre, dim3(64), dim3(256), 0, stream, x, a, cw, cb, Rpg, Ebf);
  hipLaunchKernelGGL(k_zw, dim3(NN + 256), dim3(256), 0, stream,
                     adj, Rpg, Ebf, Wm, x, cw, cb, hbfT);
  hipLaunchKernelGGL(k_gemm, dim3(64 * SPLIT), dim3(256), 81920, stream,
                     Wm, hbfT, hpF, hpH, useSplit);
  hipLaunchKernelGGL(k_epi, dim3(1024), dim3(256), 0, stream,
                     hpF, hpH, useSplit, x, cw, cb, bias, out);
}